// Round 9
// baseline (1959.618 us; speedup 1.0000x reference)
//
#include <hip/hip_runtime.h>
#include <hip/hip_bf16.h>
#include <math.h>

#define NN 100000
#define NE 1600000
#define F 128      // node feat dim (in == out)
#define EF 64      // edge feat dim
#define NH 4       // heads
#define HD 32      // head dim
#define SCAN_NBLK 98   // ceil(NN / 1024)

// ---------------------------------------------------------------------------
// K0: c[h][j] = sum_d W_proj[h*32+d][128+j] * av[h][d]   (4x64, one block)
// ---------------------------------------------------------------------------
__global__ void k_prep_c(const float* __restrict__ Wp, const float* __restrict__ av,
                         float* __restrict__ c) {
    int t = threadIdx.x;
    int h = t >> 6;
    int j = t & 63;
    float acc = 0.f;
#pragma unroll
    for (int d = 0; d < HD; ++d)
        acc += Wp[(h * HD + d) * 192 + 128 + j] * av[h * HD + d];
    c[h * EF + j] = acc;
}

// ---------------------------------------------------------------------------
// K1: P[n][k] = bias[k] + sum_{j<128} nfeats[n][j] * Wp[k][j]
// ---------------------------------------------------------------------------
__global__ __launch_bounds__(256, 3) void k_node_proj(
    const float* __restrict__ nf, const float* __restrict__ Wp,
    const float* __restrict__ bp, float* __restrict__ P) {
    __shared__ float in_t[32][129];
    __shared__ float w_t[64][129];
    int t = threadIdx.x;
    int nb = blockIdx.x * 32;
#pragma unroll
    for (int i = 0; i < 4; ++i) {
        int f4 = i * 256 + t;
        int row = f4 >> 5, c4 = f4 & 31;
        float4 v = ((const float4*)(nf + (size_t)(nb + row) * F))[c4];
        in_t[row][c4 * 4 + 0] = v.x; in_t[row][c4 * 4 + 1] = v.y;
        in_t[row][c4 * 4 + 2] = v.z; in_t[row][c4 * 4 + 3] = v.w;
    }
    int kk = t & 63, ng = t >> 6;
    for (int kh = 0; kh < 2; ++kh) {
        __syncthreads();
#pragma unroll
        for (int i = 0; i < 8; ++i) {
            int f4 = i * 256 + t;
            int row = f4 >> 5, c4 = f4 & 31;
            float4 v = *(const float4*)(Wp + (size_t)(kh * 64 + row) * 192 + c4 * 4);
            w_t[row][c4 * 4 + 0] = v.x; w_t[row][c4 * 4 + 1] = v.y;
            w_t[row][c4 * 4 + 2] = v.z; w_t[row][c4 * 4 + 3] = v.w;
        }
        __syncthreads();
        float acc[8] = {0.f, 0.f, 0.f, 0.f, 0.f, 0.f, 0.f, 0.f};
        for (int j = 0; j < 128; ++j) {
            float w = w_t[kk][j];
#pragma unroll
            for (int i = 0; i < 8; ++i)
                acc[i] += in_t[ng * 8 + i][j] * w;
        }
        float b = bp[kh * 64 + kk];
#pragma unroll
        for (int i = 0; i < 8; ++i)
            P[(size_t)(nb + ng * 8 + i) * F + kh * 64 + kk] = acc[i] + b;
    }
}

// ---------------------------------------------------------------------------
// K1b: sn[n][h] = sum_d P[n][h*32+d] * av[h][d]
// ---------------------------------------------------------------------------
__global__ void k_sn(const float* __restrict__ P, const float* __restrict__ av,
                     float* __restrict__ sn) {
    __shared__ __align__(16) float avs[128];
    int t = threadIdx.x;
    if (t < 128) avs[t] = av[t];
    __syncthreads();
    int n = blockIdx.x * 64 + (t >> 2);
    int h = t & 3;
    if (n >= NN) return;
    const float* p = P + (size_t)n * F + h * HD;
    const float* a = avs + h * HD;
    float acc = 0.f;
#pragma unroll
    for (int q = 0; q < 8; ++q) {
        float4 v = ((const float4*)p)[q];
        float4 w = ((const float4*)a)[q];
        acc += v.x * w.x + v.y * w.y + v.z * w.z + v.w * w.w;
    }
    sn[n * 4 + h] = acc;
}

// ---------------------------------------------------------------------------
// Counting sort by dst: hist -> 2-level exclusive scan -> scatter ranks
// ---------------------------------------------------------------------------
__global__ void k_hist(const int* __restrict__ dst, int* __restrict__ cnt) {
    int e = blockIdx.x * 256 + threadIdx.x;
    if (e < NE) atomicAdd(&cnt[dst[e]], 1);
}

__global__ void k_scan_a(const int* __restrict__ cnt, int* __restrict__ ro,
                         int* __restrict__ bsum) {
    __shared__ int buf[256];
    int t = threadIdx.x;
    int base = blockIdx.x * 1024 + t * 4;
    int v0 = 0, v1 = 0, v2 = 0, v3 = 0;
    if (base + 0 < NN) v0 = cnt[base + 0];
    if (base + 1 < NN) v1 = cnt[base + 1];
    if (base + 2 < NN) v2 = cnt[base + 2];
    if (base + 3 < NN) v3 = cnt[base + 3];
    int s = v0 + v1 + v2 + v3;
    buf[t] = s;
    __syncthreads();
    for (int off = 1; off < 256; off <<= 1) {
        int x = (t >= off) ? buf[t - off] : 0;
        __syncthreads();
        buf[t] += x;
        __syncthreads();
    }
    int run = buf[t] - s;   // exclusive prefix of this thread's 4
    if (base + 0 < NN) ro[base + 0] = run; run += v0;
    if (base + 1 < NN) ro[base + 1] = run; run += v1;
    if (base + 2 < NN) ro[base + 2] = run; run += v2;
    if (base + 3 < NN) ro[base + 3] = run;
    if (t == 255) bsum[blockIdx.x] = buf[255];
}

__global__ void k_scan_b(const int* __restrict__ bsum, int* __restrict__ boff) {
    __shared__ int buf[128];
    int t = threadIdx.x;
    int v = (t < SCAN_NBLK) ? bsum[t] : 0;
    buf[t] = v;
    __syncthreads();
    for (int off = 1; off < 128; off <<= 1) {
        int x = (t >= off) ? buf[t - off] : 0;
        __syncthreads();
        buf[t] += x;
        __syncthreads();
    }
    if (t < SCAN_NBLK) boff[t] = buf[t] - v;
}

__global__ void k_scan_c(int* __restrict__ ro, const int* __restrict__ boff) {
    int base = blockIdx.x * 1024 + threadIdx.x * 4;
    int add = boff[blockIdx.x];
#pragma unroll
    for (int i = 0; i < 4; ++i)
        if (base + i < NN) ro[base + i] += add;
    if (blockIdx.x == 0 && threadIdx.x == 0) ro[NN] = NE;
}

__global__ void k_scatter(const int* __restrict__ dst, const int* __restrict__ ro,
                          int* __restrict__ rank, int* __restrict__ perm) {
    int e = blockIdx.x * 256 + threadIdx.x;
    if (e < NE) {
        int d = dst[e];
        int r = atomicAdd(&rank[d], 1);
        perm[ro[d] + r] = e;
    }
}

// ---------------------------------------------------------------------------
// K_AGG2: fused score + softmax + message + aggregate, dst-sorted edges.
// Block owns 32 dst nodes. Per 64-edge chunk:
//   phase A: gather efeats -> LDS; scores -> ext; reg-tiled Q GEMM -> qt (bf16)
//   phase B: OWNER threads (t -> node t>>3, cols (t&7)*16..+16) accumulate
//            S[16] and den in REGISTERS over their node's edges in the chunk.
// Deterministic: no atomics, single-writer LDS phases fenced by barriers.
// Finalize: hne = S/den (registers -> one coalesced store).
// ---------------------------------------------------------------------------
__global__ __launch_bounds__(256, 2) void k_agg2(
    const float* __restrict__ ef, const int* __restrict__ src,
    const int* __restrict__ perm, const int* __restrict__ row_off,
    const float* __restrict__ Wp, const float* __restrict__ P,
    const float* __restrict__ sn, const float* __restrict__ c,
    float* __restrict__ hne) {
    __shared__ float wt[128][65];            // We: 33.3 KB
    __shared__ float eft[64][65];            // edge feats: 16.6 KB
    __shared__ __hip_bfloat16 qt[64][132];   // Q results:  16.9 KB
    __shared__ float ext[64][4];             // exp(score): 1 KB
    __shared__ float cs[4][64];              // 1 KB
    __shared__ int ro[33];
    __shared__ int eidx[64];
    __shared__ int sarr[64];

    int t = threadIdx.x;
    int nb = blockIdx.x * 32;

    // stage We (128x64), row stride 192 offset 128
#pragma unroll
    for (int i = 0; i < 8; ++i) {
        int f4 = i * 256 + t;
        int row = f4 >> 4, c4 = f4 & 15;
        float4 v = *(const float4*)(Wp + (size_t)row * 192 + 128 + c4 * 4);
        wt[row][c4 * 4 + 0] = v.x; wt[row][c4 * 4 + 1] = v.y;
        wt[row][c4 * 4 + 2] = v.z; wt[row][c4 * 4 + 3] = v.w;
    }
    cs[t >> 6][t & 63] = c[t];
    if (t < 33) ro[t] = row_off[nb + t];
    __syncthreads();

    int e_begin = ro[0], e_end = ro[32];
    // GEMM ids
    int kt = t & 15, et = t >> 4, e0 = et * 4;
    // score ids
    int hh = t >> 6, es = t & 63;
    // owner ids: node n_own, 16-col block q0 (q0 spans a single head)
    int n_own = t >> 3, q0 = (t & 7) * 16;
    int own_lo = ro[n_own], own_hi = ro[n_own + 1];
    int hown = q0 >> 5;
    float S[16] = {0.f, 0.f, 0.f, 0.f, 0.f, 0.f, 0.f, 0.f,
                   0.f, 0.f, 0.f, 0.f, 0.f, 0.f, 0.f, 0.f};
    float den = 0.f;

    for (int ce = e_begin; ce < e_end; ce += 64) {
        int m = min(64, e_end - ce);
        if (t < m) {
            int pe = perm[ce + t];
            eidx[t] = pe;
            sarr[t] = src[pe];
        }
        __syncthreads();
        // gather ef rows
#pragma unroll
        for (int i = 0; i < 4; ++i) {
            int f4 = i * 256 + t;
            int row = f4 >> 4, c4 = f4 & 15;
            if (row < m) {
                float4 v = ((const float4*)(ef + (size_t)eidx[row] * EF))[c4];
                eft[row][c4 * 4 + 0] = v.x; eft[row][c4 * 4 + 1] = v.y;
                eft[row][c4 * 4 + 2] = v.z; eft[row][c4 * 4 + 3] = v.w;
            }
        }
        __syncthreads();
        // score: thread = (head hh, edge es); writes ext
        if (es < m) {
            float a = sn[(size_t)sarr[es] * 4 + hh];
            const float* crow = cs[hh];
#pragma unroll 8
            for (int j = 0; j < 64; ++j) a += eft[es][j] * crow[j];
            ext[es][hh] = __expf(a);
        }
        // Q GEMM: 4 edges x 8 k per thread; writes qt (rows >= m are
        // garbage from stale eft but never read by owners)
        float acc[4][8] = {};
        for (int j = 0; j < 64; ++j) {
            float f0 = eft[e0 + 0][j], f1 = eft[e0 + 1][j];
            float f2 = eft[e0 + 2][j], f3 = eft[e0 + 3][j];
#pragma unroll
            for (int mm = 0; mm < 8; ++mm) {
                float w = wt[mm * 16 + kt][j];
                acc[0][mm] += f0 * w; acc[1][mm] += f1 * w;
                acc[2][mm] += f2 * w; acc[3][mm] += f3 * w;
            }
        }
#pragma unroll
        for (int i = 0; i < 4; ++i)
#pragma unroll
            for (int mm = 0; mm < 8; ++mm)
                qt[e0 + i][mm * 16 + kt] = __float2bfloat16(acc[i][mm]);
        __syncthreads();
        // owner accumulate: node n_own's edges within this chunk
        {
            int lo = max(own_lo, ce), hi = min(own_hi, ce + m);
            for (int e = lo; e < hi; ++e) {
                int el = e - ce;
                float exv = ext[el][hown];
                const float* pr = P + (size_t)sarr[el] * F + q0;
                den += exv;
#pragma unroll
                for (int q = 0; q < 16; q += 4) {
                    float4 pv = *(const float4*)(pr + q);
                    S[q + 0] += exv * (pv.x + __bfloat162float(qt[el][q0 + q + 0]));
                    S[q + 1] += exv * (pv.y + __bfloat162float(qt[el][q0 + q + 1]));
                    S[q + 2] += exv * (pv.z + __bfloat162float(qt[el][q0 + q + 2]));
                    S[q + 3] += exv * (pv.w + __bfloat162float(qt[el][q0 + q + 3]));
                }
            }
        }
        __syncthreads();   // fence owner reads from next chunk's overwrites
    }
    // finalize: hne[n][q0..q0+16] = S / den   (0 if deg==0)
    float rd = den > 0.f ? 1.f / den : 0.f;
    float* orow = hne + (size_t)(nb + n_own) * F + q0;
#pragma unroll
    for (int q = 0; q < 16; q += 4) {
        float4 o;
        o.x = S[q + 0] * rd; o.y = S[q + 1] * rd;
        o.z = S[q + 2] * rd; o.w = S[q + 3] * rd;
        *(float4*)(orow + q) = o;
    }
}

// ---------------------------------------------------------------------------
// K4: h = relu((hne + nf) @ Wout.T + b); out = LN(h) * gamma + beta
// ---------------------------------------------------------------------------
__global__ __launch_bounds__(256, 2) void k_node_out(
    const float* __restrict__ hne, const float* __restrict__ nf,
    const float* __restrict__ Wo, const float* __restrict__ bo,
    const float* __restrict__ gamma, const float* __restrict__ beta,
    float* __restrict__ out) {
    __shared__ float in_t[32][129];
    __shared__ float w_t[64][129];
    __shared__ float h_t[32][132];
    int t = threadIdx.x;
    int nb = blockIdx.x * 32;
#pragma unroll
    for (int i = 0; i < 4; ++i) {
        int f4 = i * 256 + t;
        int row = f4 >> 5, c4 = f4 & 31;
        float4 a = ((const float4*)(hne + (size_t)(nb + row) * F))[c4];
        float4 b = ((const float4*)(nf + (size_t)(nb + row) * F))[c4];
        in_t[row][c4 * 4 + 0] = a.x + b.x; in_t[row][c4 * 4 + 1] = a.y + b.y;
        in_t[row][c4 * 4 + 2] = a.z + b.z; in_t[row][c4 * 4 + 3] = a.w + b.w;
    }
    int kk = t & 63, ng = t >> 6;
    for (int kh = 0; kh < 2; ++kh) {
        __syncthreads();
#pragma unroll
        for (int i = 0; i < 8; ++i) {
            int f4 = i * 256 + t;
            int row = f4 >> 5, c4 = f4 & 31;
            float4 v = ((const float4*)(Wo + (size_t)(kh * 64 + row) * F))[c4];
            w_t[row][c4 * 4 + 0] = v.x; w_t[row][c4 * 4 + 1] = v.y;
            w_t[row][c4 * 4 + 2] = v.z; w_t[row][c4 * 4 + 3] = v.w;
        }
        __syncthreads();
        float acc[8] = {0.f, 0.f, 0.f, 0.f, 0.f, 0.f, 0.f, 0.f};
        for (int j = 0; j < 128; ++j) {
            float w = w_t[kk][j];
#pragma unroll
            for (int i = 0; i < 8; ++i)
                acc[i] += in_t[ng * 8 + i][j] * w;
        }
        float b = bo[kh * 64 + kk];
#pragma unroll
        for (int i = 0; i < 8; ++i) {
            float v = acc[i] + b;
            h_t[ng * 8 + i][kh * 64 + kk] = v > 0.f ? v : 0.f;
        }
    }
    __syncthreads();
    int n = t >> 3, li = t & 7;
    float s = 0.f, ss = 0.f;
    float vals[16];
#pragma unroll
    for (int q = 0; q < 16; ++q) {
        float v = h_t[n][li * 16 + q];
        vals[q] = v; s += v; ss += v * v;
    }
#pragma unroll
    for (int o = 1; o < 8; o <<= 1) {
        s += __shfl_xor(s, o, 64);
        ss += __shfl_xor(ss, o, 64);
    }
    float mu = s * (1.f / 128.f);
    float var = ss * (1.f / 128.f) - mu * mu;
    float rstd = rsqrtf(var + 1e-5f);
    float* orow = out + (size_t)(nb + n) * F + li * 16;
#pragma unroll
    for (int q4 = 0; q4 < 4; ++q4) {
        float4 o;
        int k = li * 16 + q4 * 4;
        o.x = (vals[q4 * 4 + 0] - mu) * rstd * gamma[k + 0] + beta[k + 0];
        o.y = (vals[q4 * 4 + 1] - mu) * rstd * gamma[k + 1] + beta[k + 1];
        o.z = (vals[q4 * 4 + 2] - mu) * rstd * gamma[k + 2] + beta[k + 2];
        o.w = (vals[q4 * 4 + 3] - mu) * rstd * gamma[k + 3] + beta[k + 3];
        *(float4*)(orow + q4 * 4) = o;
    }
}

// ---------------------------------------------------------------------------
extern "C" void kernel_launch(void* const* d_in, const int* in_sizes, int n_in,
                              void* d_out, int out_size, void* d_ws, size_t ws_size,
                              hipStream_t stream) {
    const float* nf    = (const float*)d_in[0];
    const float* ef    = (const float*)d_in[1];
    const int*   src   = (const int*)d_in[2];
    const int*   dst   = (const int*)d_in[3];
    const float* Wp    = (const float*)d_in[4];
    const float* bp    = (const float*)d_in[5];
    const float* av    = (const float*)d_in[6];
    const float* Wo    = (const float*)d_in[7];
    const float* bo    = (const float*)d_in[8];
    const float* gamma = (const float*)d_in[9];
    const float* beta  = (const float*)d_in[10];
    float* out = (float*)d_out;

    float* P      = (float*)d_ws;                 // NN*F
    float* sn     = P + (size_t)NN * F;           // NN*4
    float* c      = sn + (size_t)NN * 4;          // 256
    float* hne    = c + 256;                      // NN*F
    int* cnt      = (int*)(hne + (size_t)NN * F); // NN
    int* rank     = cnt + NN;                     // NN
    int* row_off  = rank + NN;                    // NN+1
    int* bsum     = row_off + NN + 1;             // 128
    int* boff     = bsum + 128;                   // 128
    int* perm     = boff + 128;                   // NE

    hipMemsetAsync(cnt, 0, (size_t)NN * sizeof(int), stream);
    hipMemsetAsync(rank, 0, (size_t)NN * sizeof(int), stream);

    k_prep_c<<<1, 256, 0, stream>>>(Wp, av, c);
    k_node_proj<<<NN / 32, 256, 0, stream>>>(nf, Wp, bp, P);
    k_sn<<<(NN + 63) / 64, 256, 0, stream>>>(P, av, sn);

    k_hist<<<(NE + 255) / 256, 256, 0, stream>>>(dst, cnt);
    k_scan_a<<<SCAN_NBLK, 256, 0, stream>>>(cnt, row_off, bsum);
    k_scan_b<<<1, 128, 0, stream>>>(bsum, boff);
    k_scan_c<<<SCAN_NBLK, 256, 0, stream>>>(row_off, boff);
    k_scatter<<<(NE + 255) / 256, 256, 0, stream>>>(dst, row_off, rank, perm);

    k_agg2<<<NN / 32, 256, 0, stream>>>(ef, src, perm, row_off, Wp, P, sn, c, hne);
    k_node_out<<<NN / 32, 256, 0, stream>>>(hne, nf, Wo, bo, gamma, beta, out);
}